// Round 1
// baseline (105.622 us; speedup 1.0000x reference)
//
#include <hip/hip_runtime.h>

// CenterLoss: loss = mean_b( ||feat[b] - centers[label[b]]|| / count[label[b]] )
// feat: [16384, 512] f32, label: [16384] i32, centers: [10000, 512] f32 -> scalar f32

constexpr int NUM_CLASSES = 10000;
constexpr int FEATURE_DIM = 512;
constexpr int BATCH       = 16384;
constexpr int SAMPLES_PER_BLOCK = 16;   // 4 waves x 4 samples each -> 1024 blocks, 1024 atomics

__global__ __launch_bounds__(256) void center_hist_kernel(const int* __restrict__ label,
                                                          int* __restrict__ count) {
    int i = blockIdx.x * blockDim.x + threadIdx.x;
    if (i < BATCH) {
        atomicAdd(&count[label[i]], 1);
    }
}

__global__ __launch_bounds__(256) void center_dist_kernel(const float* __restrict__ feat,
                                                          const int* __restrict__ label,
                                                          const float* __restrict__ centers,
                                                          const int* __restrict__ count,
                                                          float* __restrict__ out) {
    __shared__ float wave_part[4];
    const int wave = threadIdx.x >> 6;   // 0..3
    const int lane = threadIdx.x & 63;   // 0..63

    float local = 0.0f;  // meaningful on lane 0 of each wave
    const int base = blockIdx.x * SAMPLES_PER_BLOCK;

    // Each wave handles SAMPLES_PER_BLOCK/4 samples.
    for (int s = wave; s < SAMPLES_PER_BLOCK; s += 4) {
        const int b = base + s;                 // grid sized exactly; b < BATCH always
        const int lab = label[b];

        const float4* f4 = reinterpret_cast<const float4*>(feat    + (size_t)b   * FEATURE_DIM);
        const float4* c4 = reinterpret_cast<const float4*>(centers + (size_t)lab * FEATURE_DIM);

        // Lane i covers elements [4i, 4i+4) and [256+4i, 256+4i+4): two fully
        // coalesced 16B-per-lane vector loads per operand (64 lanes x 4 floats = 256).
        float4 fa = f4[lane];
        float4 fb = f4[lane + 64];
        float4 ca = c4[lane];
        float4 cb = c4[lane + 64];

        float d0 = fa.x - ca.x, d1 = fa.y - ca.y, d2 = fa.z - ca.z, d3 = fa.w - ca.w;
        float d4 = fb.x - cb.x, d5 = fb.y - cb.y, d6 = fb.z - cb.z, d7 = fb.w - cb.w;
        float s2 = d0*d0 + d1*d1 + d2*d2 + d3*d3 + d4*d4 + d5*d5 + d6*d6 + d7*d7;

        // 64-lane reduction (wave = 64 on CDNA).
        #pragma unroll
        for (int off = 32; off > 0; off >>= 1) {
            s2 += __shfl_down(s2, off, 64);
        }

        if (lane == 0) {
            float dist = sqrtf(s2);
            local += dist / (float)count[lab];
        }
    }

    if (lane == 0) wave_part[wave] = local;
    __syncthreads();

    if (threadIdx.x == 0) {
        float sum = wave_part[0] + wave_part[1] + wave_part[2] + wave_part[3];
        atomicAdd(out, sum * (1.0f / (float)BATCH));
    }
}

extern "C" void kernel_launch(void* const* d_in, const int* in_sizes, int n_in,
                              void* d_out, int out_size, void* d_ws, size_t ws_size,
                              hipStream_t stream) {
    const float* feat    = (const float*)d_in[0];
    const int*   label   = (const int*)  d_in[1];
    const float* centers = (const float*)d_in[2];
    float*       out     = (float*)d_out;
    int*         count   = (int*)d_ws;

    // d_ws and d_out are poisoned (0xAA) before every timed launch — zero them.
    hipMemsetAsync(count, 0, NUM_CLASSES * sizeof(int), stream);
    hipMemsetAsync(out,   0, sizeof(float), stream);

    center_hist_kernel<<<(BATCH + 255) / 256, 256, 0, stream>>>(label, count);

    center_dist_kernel<<<BATCH / SAMPLES_PER_BLOCK, 256, 0, stream>>>(
        feat, label, centers, count, out);
}

// Round 2
// 105.610 us; speedup vs baseline: 1.0001x; 1.0001x over previous
//
#include <hip/hip_runtime.h>

// CenterLoss: loss = mean_b( ||feat[b] - centers[label[b]]|| / count[label[b]] )
// feat: [16384, 512] f32, label: [16384] i32, centers: [10000, 512] f32 -> scalar f32
//
// 2 dispatches total:
//  K1: bin-ownership histogram (no global pre-zero needed) + zeroes d_out
//  K2: one wave per sample, float4-coalesced distance + block-reduced atomic

constexpr int NUM_CLASSES = 10000;
constexpr int FEATURE_DIM = 512;
constexpr int BATCH       = 16384;
constexpr int SAMPLES_PER_BLOCK = 16;   // 4 waves x 4 samples each -> 1024 blocks

constexpr int HIST_BLOCKS    = 20;
constexpr int BINS_PER_BLOCK = NUM_CLASSES / HIST_BLOCKS;  // 500

// Each block OWNS bins [blockIdx*500, +500): zero in LDS, scan all labels,
// plain-store its slice. No cross-block races -> no global memset required.
__global__ __launch_bounds__(1024) void center_hist_kernel(const int* __restrict__ label,
                                                           int* __restrict__ count,
                                                           float* __restrict__ out) {
    __shared__ int h[BINS_PER_BLOCK];
    const int lo = blockIdx.x * BINS_PER_BLOCK;

    for (int i = threadIdx.x; i < BINS_PER_BLOCK; i += 1024) h[i] = 0;
    __syncthreads();

    for (int i = threadIdx.x; i < BATCH; i += 1024) {
        int lab = label[i] - lo;
        if ((unsigned)lab < (unsigned)BINS_PER_BLOCK) atomicAdd(&h[lab], 1);
    }
    __syncthreads();

    for (int i = threadIdx.x; i < BINS_PER_BLOCK; i += 1024) count[lo + i] = h[i];

    if (blockIdx.x == 0 && threadIdx.x == 0) out[0] = 0.0f;  // K2 accumulates on top
}

__global__ __launch_bounds__(256) void center_dist_kernel(const float* __restrict__ feat,
                                                          const int* __restrict__ label,
                                                          const float* __restrict__ centers,
                                                          const int* __restrict__ count,
                                                          float* __restrict__ out) {
    __shared__ float wave_part[4];
    const int wave = threadIdx.x >> 6;   // 0..3
    const int lane = threadIdx.x & 63;   // 0..63

    float local = 0.0f;  // meaningful on lane 0 of each wave
    const int base = blockIdx.x * SAMPLES_PER_BLOCK;

    // Each wave handles SAMPLES_PER_BLOCK/4 samples.
    for (int s = wave; s < SAMPLES_PER_BLOCK; s += 4) {
        const int b = base + s;                 // grid sized exactly; b < BATCH always
        const int lab = label[b];               // wave-uniform -> scalar load

        const float4* f4 = reinterpret_cast<const float4*>(feat    + (size_t)b   * FEATURE_DIM);
        const float4* c4 = reinterpret_cast<const float4*>(centers + (size_t)lab * FEATURE_DIM);

        // Lane i covers elements [4i,4i+4) and [256+4i, ...): two fully
        // coalesced 16B-per-lane vector loads per operand.
        float4 fa = f4[lane];
        float4 fb = f4[lane + 64];
        float4 ca = c4[lane];
        float4 cb = c4[lane + 64];

        float d0 = fa.x - ca.x, d1 = fa.y - ca.y, d2 = fa.z - ca.z, d3 = fa.w - ca.w;
        float d4 = fb.x - cb.x, d5 = fb.y - cb.y, d6 = fb.z - cb.z, d7 = fb.w - cb.w;
        float s2 = d0*d0 + d1*d1 + d2*d2 + d3*d3 + d4*d4 + d5*d5 + d6*d6 + d7*d7;

        // 64-lane butterfly reduction (wave = 64 on CDNA).
        #pragma unroll
        for (int off = 32; off > 0; off >>= 1) {
            s2 += __shfl_down(s2, off, 64);
        }

        if (lane == 0) {
            float dist = sqrtf(s2);
            local += dist / (float)count[lab];
        }
    }

    if (lane == 0) wave_part[wave] = local;
    __syncthreads();

    if (threadIdx.x == 0) {
        float sum = wave_part[0] + wave_part[1] + wave_part[2] + wave_part[3];
        atomicAdd(out, sum * (1.0f / (float)BATCH));  // 1024 atomics total
    }
}

extern "C" void kernel_launch(void* const* d_in, const int* in_sizes, int n_in,
                              void* d_out, int out_size, void* d_ws, size_t ws_size,
                              hipStream_t stream) {
    const float* feat    = (const float*)d_in[0];
    const int*   label   = (const int*)  d_in[1];
    const float* centers = (const float*)d_in[2];
    float*       out     = (float*)d_out;
    int*         count   = (int*)d_ws;

    center_hist_kernel<<<HIST_BLOCKS, 1024, 0, stream>>>(label, count, out);

    center_dist_kernel<<<BATCH / SAMPLES_PER_BLOCK, 256, 0, stream>>>(
        feat, label, centers, count, out);
}